// Round 5
// baseline (468.404 us; speedup 1.0000x reference)
//
#include <hip/hip_runtime.h>

// Problem constants (B=64, C=D=64, H=W=64, K=1024)
#define K_CODES 1024
#define D_DIM   64
#define N_ROWS  262144      // B*H*W
#define HW      4096        // H*W
#define CHW     262144      // C*H*W
#define N_ELEM  16777216    // B*C*H*W
#define DECAY   0.99f
#define OMD     0.01f       // 1 - DECAY
#define EPS_F   1e-05f
// Max-domain margin (acc units: m = dot - w^2/2; dist-gap = 2*acc-gap).
#define MARGIN_ACC 0.004f
#define FLAG_CAP 32768      // expected flags ~1-6k
#define SEG_CAP  2048       // per-code row cap (mean 256, Poisson max ~340)
#define NHB      64         // hist blocks (4096 rows each)
#define BROWS    256        // rows per argmin block (64 per wave)

typedef __attribute__((ext_vector_type(8))) short bf16x8;  // 8 bf16 = 4 VGPRs
typedef __attribute__((ext_vector_type(4))) float f32x4;

// Workspace layout (bytes); [0,64) is the only zeroed region. All 16B-aligned.
constexpr size_t OFF_LOSS    = 0;        // 1 double
constexpr size_t OFF_FLAGCNT = 8;        // 1 int
constexpr size_t OFF_DONE    = 12;       // 1 int (out_kernel completion count)
constexpr size_t OFF_HDONE   = 16;       // 1 int (hist completion count)
constexpr size_t OFF_W2F     = 64;       // 1024 f   -> 4160
constexpr size_t OFF_W2D     = 4160;     // 1024 d   -> 12352
constexpr size_t OFF_CS     = 12352;     // 1024 f   -> 16448
constexpr size_t OFF_GOFF    = 16448;    // 1025 i   -> 20608 (padded)
constexpr size_t OFF_NEWW    = 282752;   // 65536 f  -> 544896
constexpr size_t OFF_IDX     = 544896;   // 262144 i -> 1593472
constexpr size_t OFF_HISTB   = 1593472;  // 64x1024 i -> 1855616
constexpr size_t OFF_SORT    = 1855616;  // 262144 i -> 2904192
constexpr size_t OFF_FLAGS   = 1855616;  // 32768 i (dead after refine)
constexpr size_t OFF_WFRAG   = 1986688;  // 131072 bf16 (dead after argmin)

__device__ __forceinline__ short f2bf(float f) {  // RNE float->bf16
    unsigned u = __float_as_uint(f);
    u += 0x7fffu + ((u >> 16) & 1u);
    return (short)(u >> 16);
}
__device__ __forceinline__ float bf2f(short h) {
    return __uint_as_float(((unsigned)(unsigned short)h) << 16);
}

__device__ __forceinline__ void gload_lds16(const float4* g, void* l) {
    __builtin_amdgcn_global_load_lds(
        (const __attribute__((address_space(1))) void*)g,
        (__attribute__((address_space(3))) void*)l, 16, 0, 0);
}

// One-time prep: W swizzled to bf16 hi/lo B-fragment pairs for 16x16x32 MFMA.
// Block 35 threads 0..7 zero the scalar counters (loss/flagcnt/done/hist_done).
__global__ __launch_bounds__(256) void prep_kernel(
    const float* __restrict__ w, short* __restrict__ wfrag,
    float* __restrict__ w2f, double* __restrict__ w2d,
    int* __restrict__ zero16) {
    int t = threadIdx.x;
    if (blockIdx.x == 35 && t < 8) zero16[t] = 0;
    if (blockIdx.x < 32) {
        int gid = blockIdx.x * 256 + t;  // (j<<7)|(h<<6)|L
        int j = gid >> 7, h = (gid >> 6) & 1, L = gid & 63;
        int code = j * 16 + (L & 15);
        int kb = h * 32 + ((L >> 4) << 3);
        const float* wp = w + code * D_DIM + kb;
        short hi[8], lo[8];
#pragma unroll
        for (int i = 0; i < 8; ++i) {
            float v = wp[i];
            short hb = f2bf(v);
            hi[i] = hb;
            lo[i] = f2bf(v - bf2f(hb));
        }
        short* dh = wfrag + (size_t)(((j * 2 + h) * 2 + 0) * 64 + L) * 8;
        short* dl = wfrag + (size_t)(((j * 2 + h) * 2 + 1) * 64 + L) * 8;
#pragma unroll
        for (int i = 0; i < 8; ++i) { dh[i] = hi[i]; dl[i] = lo[i]; }
    } else {
        int k = (blockIdx.x - 32) * 256 + t;
        const float* wk = w + k * D_DIM;
        float sf = 0.f; double sd = 0.0;
#pragma unroll
        for (int d = 0; d < D_DIM; ++d) {
            float wv = wk[d];
            sf = fmaf(wv, wv, sf);
            sd = fma((double)wv, (double)wv, sd);
        }
        w2f[k] = sf; w2d[k] = sd;
    }
}

// Split-bf16 MFMA argmin. R11: 64 rows/wave (256/block, 1024 blocks).
// R4's PMC model: MFMA pipe 39% (the floor), LDS-read pipe 32%, scoreboard
// VALU ~16% — nothing saturated -> overlap-bound. LDS B-fragment traffic
// scales with WAVE count (each wave reads all 256KB of wfrag), so 64 rows/
// wave halves it again (98K -> 49K cyc/CU) and gives each ds_read_b128 a
// 4-deep independent MFMA chain. VGPR ~150-170 at waves_per_eu(3,4) ->
// 3 waves/SIMD — same 12 waves/CU as R4 measured, with half the LDS/barrier
// overhead. x staged in FOUR 64-row passes through the 17.4KB xs buffer.
__global__ __launch_bounds__(256) __attribute__((amdgpu_waves_per_eu(3, 4)))
void argmin_kernel(
    const float* __restrict__ inp, const short* __restrict__ wfrag,
    const float* __restrict__ w2f, int* __restrict__ idx_ws,
    float* __restrict__ out_idx_f, float* __restrict__ xt,
    int* __restrict__ flagcnt, int* __restrict__ flaglist) {
    __shared__ float w2s[K_CODES];
    __shared__ alignas(16) char smem_u[64 * 68 * 4];  // xs(17408B) / bufB(16KB) union
    __shared__ alignas(16) short bufA[8192];          // 16 KB
    float (*xs)[68] = (float (*)[68])smem_u;          // +4 pad per row
    short* bufB = (short*)smem_u;

    int t = threadIdx.x;
    ((float4*)w2s)[t] = ((const float4*)w2f)[t];

    int rowbase = blockIdx.x * BROWS;
    int b = rowbase >> 12, hwb = rowbase & (HW - 1);
    const float* xp = inp + (size_t)b * CHW + hwb;
    int lane = t & 63, wave = t >> 6;
    int q = lane >> 4, col = lane & 15;

    bf16x8 aH[4][2], aL[4][2];  // [row-set][k-half]; built in owning pass

    // Four staging passes: pass p covers block rows p*64..p*64+63; wave p
    // builds its A-fragments from that pass.
#pragma unroll
    for (int p = 0; p < 4; ++p) {
#pragma unroll
        for (int it = 0; it < 16; ++it) {
            int d = wave * 16 + it;
            xs[lane][d] = xp[(size_t)d * HW + p * 64 + lane];  // coalesced 256B
        }
        __syncthreads();

        // xt side-product: coalesced row-major dump of these 64 rows
        float4* xt4 = (float4*)(xt + (size_t)(rowbase + p * 64) * D_DIM);
#pragma unroll
        for (int i2 = 0; i2 < 4; ++i2) {
            int c2 = t + i2 * 256;
            xt4[c2] = ((const float4*)xs[c2 >> 4])[c2 & 15];
        }

        if (wave == p) {
#pragma unroll
            for (int s2 = 0; s2 < 4; ++s2) {
                int rl = s2 * 16 + col;  // A row m = lane&15
#pragma unroll
                for (int h = 0; h < 2; ++h) {
#pragma unroll
                    for (int i = 0; i < 8; ++i) {
                        float v = xs[rl][h * 32 + q * 8 + i];
                        short hb = f2bf(v);
                        aH[s2][h][i] = hb;
                        aL[s2][h][i] = f2bf(v - bf2f(hb));
                    }
                }
            }
        }
        __syncthreads();  // all xs reads done before overwrite / bufB use
    }

    // Max-domain tracking: best = largest acc (smallest dist), best2 = 2nd.
    float best[4][4], best2[4][4];
#pragma unroll
    for (int s2 = 0; s2 < 4; ++s2)
#pragma unroll
        for (int r = 0; r < 4; ++r) { best[s2][r] = -3.4e38f; best2[s2][r] = -3.4e38f; }
    const float4* wsrc = (const float4*)wfrag;

    // Prologue: issue supertile 0 into bufA.
    {
        const float4* src = wsrc + t;
        char* nb = (char*)bufA + wave * 1024;
#pragma unroll
        for (int i2 = 0; i2 < 4; ++i2)
            gload_lds16(src + i2 * 256, nb + i2 * 4096);
    }

#define MFMA16(A, B, C) __builtin_amdgcn_mfma_f32_16x16x32_bf16(A, B, C, 0, 0, 0)

    for (int st = 0; st < 16; ++st) {
        asm volatile("s_waitcnt vmcnt(0)" ::: "memory");
        __syncthreads();
        if (st < 15) {
            const float4* src = wsrc + (size_t)(st + 1) * 1024 + t;
            char* nb = ((st & 1) ? (char*)bufA : (char*)bufB) + wave * 1024;
#pragma unroll
            for (int i2 = 0; i2 < 4; ++i2)
                gload_lds16(src + i2 * 256, nb + i2 * 4096);
        }
        const bf16x8* wt = (const bf16x8*)((st & 1) ? bufB : bufA);

#pragma unroll
        for (int jj = 0; jj < 4; ++jj) {
            int j = st * 4 + jj;
            bf16x8 bh0 = wt[(jj * 4 + 0) * 64 + lane];
            bf16x8 bl0 = wt[(jj * 4 + 1) * 64 + lane];
            bf16x8 bh1 = wt[(jj * 4 + 2) * 64 + lane];
            bf16x8 bl1 = wt[(jj * 4 + 3) * 64 + lane];
            float cj = -0.5f * w2s[j * 16 + col];
            f32x4 ac0 = {cj, cj, cj, cj}, ac1 = {cj, cj, cj, cj};
            f32x4 ac2 = {cj, cj, cj, cj}, ac3 = {cj, cj, cj, cj};
            // lo(x)·hi(w)
            ac0 = MFMA16(aL[0][0], bh0, ac0); ac1 = MFMA16(aL[1][0], bh0, ac1);
            ac2 = MFMA16(aL[2][0], bh0, ac2); ac3 = MFMA16(aL[3][0], bh0, ac3);
            ac0 = MFMA16(aL[0][1], bh1, ac0); ac1 = MFMA16(aL[1][1], bh1, ac1);
            ac2 = MFMA16(aL[2][1], bh1, ac2); ac3 = MFMA16(aL[3][1], bh1, ac3);
            // hi(x)·lo(w)
            ac0 = MFMA16(aH[0][0], bl0, ac0); ac1 = MFMA16(aH[1][0], bl0, ac1);
            ac2 = MFMA16(aH[2][0], bl0, ac2); ac3 = MFMA16(aH[3][0], bl0, ac3);
            ac0 = MFMA16(aH[0][1], bl1, ac0); ac1 = MFMA16(aH[1][1], bl1, ac1);
            ac2 = MFMA16(aH[2][1], bl1, ac2); ac3 = MFMA16(aH[3][1], bl1, ac3);
            // hi(x)·hi(w)
            ac0 = MFMA16(aH[0][0], bh0, ac0); ac1 = MFMA16(aH[1][0], bh0, ac1);
            ac2 = MFMA16(aH[2][0], bh0, ac2); ac3 = MFMA16(aH[3][0], bh0, ac3);
            ac0 = MFMA16(aH[0][1], bh1, ac0); ac1 = MFMA16(aH[1][1], bh1, ac1);
            ac2 = MFMA16(aH[2][1], bh1, ac2); ac3 = MFMA16(aH[3][1], bh1, ac3);
#pragma unroll
            for (int s2 = 0; s2 < 4; ++s2) {
                f32x4 av = (s2 == 0) ? ac0 : (s2 == 1) ? ac1 : (s2 == 2) ? ac2 : ac3;
#pragma unroll
                for (int r = 0; r < 4; ++r) {
                    // pack 6-bit j into low mantissa (<=64 ULP, covered by
                    // MARGIN_ACC + refine)
                    float key = __int_as_float((__float_as_int(av[r]) & ~63) | j);
                    best2[s2][r] = fmaxf(best2[s2][r], fminf(best[s2][r], key));
                    best[s2][r]  = fmaxf(best[s2][r], key);
                }
            }
        }
    }
#undef MFMA16

    // Unpack candidate index from key bits.
    int bk[4][4];
#pragma unroll
    for (int s2 = 0; s2 < 4; ++s2)
#pragma unroll
        for (int r = 0; r < 4; ++r)
            bk[s2][r] = ((__float_as_int(best[s2][r]) & 63) << 4) | col;

#pragma unroll
    for (int m = 1; m < 16; m <<= 1) {
#pragma unroll
        for (int s2 = 0; s2 < 4; ++s2) {
#pragma unroll
            for (int r = 0; r < 4; ++r) {
                float ob  = __shfl_xor(best[s2][r], m, 64);
                float ob2 = __shfl_xor(best2[s2][r], m, 64);
                int   obk = __shfl_xor(bk[s2][r], m, 64);
                float nb2 = fmaxf(fmaxf(best2[s2][r], ob2),
                                  fminf(best[s2][r], ob));
                int   nbk = ob > best[s2][r] ? obk
                            : (best[s2][r] > ob ? bk[s2][r]
                                                : min(bk[s2][r], obk));
                best[s2][r]  = fmaxf(best[s2][r], ob);
                best2[s2][r] = nb2;
                bk[s2][r]    = nbk;
            }
        }
    }

    if (col == 0) {
#pragma unroll
        for (int s2 = 0; s2 < 4; ++s2) {
#pragma unroll
            for (int r = 0; r < 4; ++r) {
                int row = rowbase + wave * 64 + s2 * 16 + q * 4 + r;
                idx_ws[row]    = bk[s2][r];
                out_idx_f[row] = (float)bk[s2][r];
                if (best[s2][r] - best2[s2][r] < MARGIN_ACC) {
                    int pos = atomicAdd(flagcnt, 1);
                    if (pos < FLAG_CAP) flaglist[pos] = row;
                }
            }
        }
    }
}

// fp64 rescan of flagged rows (exact); wave-per-row.
__global__ __launch_bounds__(256) void refine_kernel(
    const float* __restrict__ xt, const float* __restrict__ weight,
    const double* __restrict__ w2d, int* __restrict__ idx_ws,
    float* __restrict__ out_idx_f, const int* __restrict__ flagcnt,
    const int* __restrict__ flaglist) {
    __shared__ float sx[4][64];
    int cnt = *flagcnt;
    if (cnt > FLAG_CAP) cnt = FLAG_CAP;
    int t = threadIdx.x, lane = t & 63, wave = t >> 6;

    for (int r = blockIdx.x * 4 + wave; r < cnt; r += gridDim.x * 4) {
        int row = flaglist[r];
        sx[wave][lane] = xt[(size_t)row * D_DIM + lane];
        asm volatile("s_waitcnt lgkmcnt(0)" ::: "memory");

        double bd = 1.0e300; int bi = 0;
        int k0 = lane * 16;
#pragma unroll 4
        for (int c = 0; c < 16; ++c) {
            int k = k0 + c;
            const float4* wk4 = (const float4*)(weight + (size_t)k * D_DIM);
            double dot = 0.0;
#pragma unroll
            for (int d4 = 0; d4 < 16; ++d4) {
                float4 wv = wk4[d4];
                dot = fma((double)wv.x, (double)sx[wave][d4 * 4 + 0], dot);
                dot = fma((double)wv.y, (double)sx[wave][d4 * 4 + 1], dot);
                dot = fma((double)wv.z, (double)sx[wave][d4 * 4 + 2], dot);
                dot = fma((double)wv.w, (double)sx[wave][d4 * 4 + 3], dot);
            }
            double dist = w2d[k] - 2.0 * dot;  // x^2 omitted (constant)
            if (dist < bd) { bd = dist; bi = k; }
        }
#pragma unroll
        for (int m = 1; m < 64; m <<= 1) {
            double od = __shfl_xor(bd, m, 64);
            int    oi = __shfl_xor(bi, m, 64);
            if (od < bd || (od == bd && oi < bi)) { bd = od; bi = oi; }
        }
        if (lane == 0 && bi != idx_ws[row]) {
            idx_ws[row]    = bi;
            out_idx_f[row] = (float)bi;
        }
    }
}

// Counting sort pass 1 + FUSED scan (R11): per-block LDS histogram; the last
// block to finish (done-counter, same pattern as out_kernel's loss) performs
// the column prefix + global exclusive prefix + cursors + Laplace/csn —
// removes the separate 1-block scan launch. Cross-XCD visibility: writers
// __threadfence() before the counter add; the reader's caches are cold for
// other blocks' histb lines, so plain loads fetch fresh data.
__global__ __launch_bounds__(256) void hist_kernel(
    const int* __restrict__ idx_ws, int* __restrict__ histb,
    int* __restrict__ hist_done, const float* __restrict__ ema_cs,
    float* __restrict__ csbuf, int* __restrict__ goff) {
    __shared__ int h[K_CODES];
    int t = threadIdx.x, b = blockIdx.x;
    for (int i = t; i < K_CODES; i += 256) h[i] = 0;
    __syncthreads();
    const int4* idx4 = (const int4*)idx_ws + b * 1024;
#pragma unroll
    for (int i = 0; i < 4; ++i) {
        int4 c = idx4[t + i * 256];
        atomicAdd(&h[c.x], 1); atomicAdd(&h[c.y], 1);
        atomicAdd(&h[c.z], 1); atomicAdd(&h[c.w], 1);
    }
    __syncthreads();
    for (int i = t; i < K_CODES; i += 256) histb[b * K_CODES + i] = h[i];

    __shared__ int amLast;
    if (t == 0) {
        __threadfence();
        amLast = (atomicAdd(hist_done, 1) == NHB - 1);
    }
    __syncthreads();
    if (!amLast) return;

    // ---- fused scan phase (one block, 256 threads, 4 codes/thread) ----
    __shared__ int   pre[256];
    __shared__ float redf[256];
    int cnt4[4]; int mysum = 0;
#pragma unroll
    for (int c = 0; c < 4; ++c) {
        int k = t * 4 + c;
        int s = 0;
        for (int b2 = 0; b2 < NHB; ++b2) {
            int v = histb[b2 * K_CODES + k];
            histb[b2 * K_CODES + k] = s;  // local exclusive prefix
            s += v;
        }
        cnt4[c] = s; mysum += s;
    }
    pre[t] = mysum;
    __syncthreads();
    for (int d = 1; d < 256; d <<= 1) {
        int v = (t >= d) ? pre[t - d] : 0;
        __syncthreads();
        if (t >= d) pre[t] += v;
        __syncthreads();
    }
    int kb = pre[t] - mysum;  // exclusive prefix of this thread's group
    float css[4]; float mycs = 0.f;
#pragma unroll
    for (int c = 0; c < 4; ++c) {
        int k = t * 4 + c;
        goff[k] = kb;
        for (int b2 = 0; b2 < NHB; ++b2) histb[b2 * K_CODES + k] += kb;
        kb += cnt4[c];
        css[c] = ema_cs[k] * DECAY + OMD * (float)cnt4[c];
        mycs += css[c];
    }
    if (t == 255) goff[K_CODES] = kb;
    redf[t] = mycs;
    __syncthreads();
    for (int s2 = 128; s2 > 0; s2 >>= 1) {
        if (t < s2) redf[t] += redf[t + s2];
        __syncthreads();
    }
    float n = redf[0];
#pragma unroll
    for (int c = 0; c < 4; ++c) {
        int k = t * 4 + c;
        csbuf[k] = (css[c] + EPS_F) / (n + (float)K_CODES * EPS_F) * n;
    }
}

// Pass 3: scatter row ids into code-sorted order via LDS cursors.
__global__ __launch_bounds__(256) void scatter_kernel(
    const int* __restrict__ idx_ws, const int* __restrict__ histb,
    int* __restrict__ sorted) {
    __shared__ int cur[K_CODES];
    int t = threadIdx.x, b = blockIdx.x;
    for (int i = t; i < K_CODES; i += 256) cur[i] = histb[b * K_CODES + i];
    __syncthreads();
    const int4* idx4 = (const int4*)idx_ws + b * 1024;
#pragma unroll
    for (int i = 0; i < 4; ++i) {
        int4 c = idx4[t + i * 256];
        int r0 = (b * 1024 + t + i * 256) * 4;
        sorted[atomicAdd(&cur[c.x], 1)] = r0 + 0;
        sorted[atomicAdd(&cur[c.y], 1)] = r0 + 1;
        sorted[atomicAdd(&cur[c.z], 1)] = r0 + 2;
        sorted[atomicAdd(&cur[c.w], 1)] = r0 + 3;
    }
}

// Pass 4: one block per code; gather xt rows, LDS tree, fused EMA+normalize.
__global__ __launch_bounds__(256) void dwred_kernel(
    const float* __restrict__ xt, const int* __restrict__ sorted,
    const int* __restrict__ goff, const float* __restrict__ ema_w,
    const float* __restrict__ csbuf, float* __restrict__ new_w) {
    __shared__ int   rows[SEG_CAP];
    __shared__ float red[256];
    int k = blockIdx.x, t = threadIdx.x;
    int base = goff[k];
    int cnt = goff[k + 1] - base;
    int cc = cnt > SEG_CAP ? SEG_CAP : cnt;

    for (int i = t; i < cc; i += 256) rows[i] = sorted[base + i];
    __syncthreads();

    int d = t & 63, sub = t >> 6;
    float a0 = 0.f, a1 = 0.f;
    int i = sub;
    for (; i + 4 < cc; i += 8) {
        a0 += xt[(size_t)rows[i] * D_DIM + d];
        a1 += xt[(size_t)rows[i + 4] * D_DIM + d];
    }
    for (; i < cc; i += 4) a0 += xt[(size_t)rows[i] * D_DIM + d];
    red[t] = a0 + a1;
    __syncthreads();
    if (t < 64) {
        float dwv = red[t] + red[t + 64] + red[t + 128] + red[t + 192];
        new_w[k * D_DIM + t] =
            (ema_w[k * D_DIM + t] * DECAY + OMD * dwv) / csbuf[k];
    }
}

// Gather updated codebook, straight-through output, commitment-loss partials.
__global__ __launch_bounds__(256) void out_kernel(
    const float* __restrict__ inp, const float* __restrict__ new_w,
    const int* __restrict__ idx_ws, float* __restrict__ out,
    double* __restrict__ loss_acc, int* __restrict__ done_cnt) {
    int row = blockIdx.x * 256 + threadIdx.x;
    int b  = row >> 12;
    int hw = row & (HW - 1);
    const float* xp = inp + (size_t)b * CHW + hw;
    float* op = out + 1 + (size_t)b * CHW + hw;  // out[0] is the loss scalar

    int k = idx_ws[row];
    const float* q = new_w + k * D_DIM;

    float lsum = 0.f;
#pragma unroll
    for (int d = 0; d < D_DIM; ++d) {
        float xv = xp[(size_t)d * HW];
        float qv = q[d];
        float diff = qv - xv;            // stop_gradient(quantized) - x
        lsum = fmaf(diff, diff, lsum);
        op[(size_t)d * HW] = xv + diff;  // x + (quantized - x)
    }

    __shared__ double lred[256];
    lred[threadIdx.x] = (double)lsum;
    __syncthreads();
    for (int s = 128; s > 0; s >>= 1) {
        if (threadIdx.x < s) lred[threadIdx.x] += lred[threadIdx.x + s];
        __syncthreads();
    }
    if (threadIdx.x == 0) {
        atomicAdd(loss_acc, lred[0]);
        __threadfence();
        int old = atomicAdd(done_cnt, 1);
        if (old == (int)gridDim.x - 1) {
            double v = atomicAdd(loss_acc, 0.0);
            out[0] = (float)(0.25 * (v / (double)N_ELEM));
        }
    }
}

extern "C" void kernel_launch(void* const* d_in, const int* in_sizes, int n_in,
                              void* d_out, int out_size, void* d_ws, size_t ws_size,
                              hipStream_t stream) {
    const float* inp    = (const float*)d_in[0];
    const float* weight = (const float*)d_in[1];
    const float* ema_cs = (const float*)d_in[2];
    const float* ema_w  = (const float*)d_in[3];
    float* out = (float*)d_out;

    char* ws = (char*)d_ws;
    double* loss_acc = (double*)(ws + OFF_LOSS);
    int*    flagcnt  = (int*)(ws + OFF_FLAGCNT);
    int*    done_cnt = (int*)(ws + OFF_DONE);
    int*    hdone    = (int*)(ws + OFF_HDONE);
    float*  w2f      = (float*)(ws + OFF_W2F);
    double* w2d      = (double*)(ws + OFF_W2D);
    float*  csbuf    = (float*)(ws + OFF_CS);
    int*    goff     = (int*)(ws + OFF_GOFF);
    float*  new_w    = (float*)(ws + OFF_NEWW);
    int*    idx_ws   = (int*)(ws + OFF_IDX);
    int*    histb    = (int*)(ws + OFF_HISTB);
    int*    sorted   = (int*)(ws + OFF_SORT);
    int*    flaglist = (int*)(ws + OFF_FLAGS);
    short*  wfrag    = (short*)(ws + OFF_WFRAG);

    float* xt        = out + 1;               // scratch: overwritten by out_kernel
    float* out_idx_f = out + 1 + (size_t)N_ELEM;

    prep_kernel<<<36, 256, 0, stream>>>(weight, wfrag, w2f, w2d, (int*)ws);

    argmin_kernel<<<N_ROWS / BROWS, 256, 0, stream>>>(
        inp, wfrag, w2f, idx_ws, out_idx_f, xt, flagcnt, flaglist);

    refine_kernel<<<512, 256, 0, stream>>>(
        xt, weight, w2d, idx_ws, out_idx_f, flagcnt, flaglist);

    hist_kernel<<<NHB, 256, 0, stream>>>(idx_ws, histb, hdone,
                                         ema_cs, csbuf, goff);

    scatter_kernel<<<NHB, 256, 0, stream>>>(idx_ws, histb, sorted);

    dwred_kernel<<<K_CODES, 256, 0, stream>>>(xt, sorted, goff, ema_w, csbuf, new_w);

    out_kernel<<<N_ROWS / 256, 256, 0, stream>>>(inp, new_w, idx_ws, out,
                                                 loss_acc, done_cnt);
}